// Round 1
// baseline (654.161 us; speedup 1.0000x reference)
//
#include <hip/hip_runtime.h>
#include <math.h>

#define B_ROWS 32768
#define K_CODES 4096
#define D_DIM 128

// ---------------------------------------------------------------------------
// Kernel 1: row sums of squares, replicating numpy pairwise_sum for n=128:
// 8 strided accumulators r[j] = sum_{i = j mod 8} fl(x_i*x_i), then
// ((r0+r1)+(r2+r3)) + ((r4+r5)+(r6+r7)).  8 lanes per row; xor-tree matches
// the combine exactly (fp add is commutative bitwise).
// ---------------------------------------------------------------------------
__global__ __launch_bounds__(256) void sq_rows(const float* __restrict__ x,
                                               const float* __restrict__ emb,
                                               float* __restrict__ x2,
                                               float* __restrict__ e2) {
  int row = blockIdx.x * 32 + (threadIdx.x >> 3);
  int lane = threadIdx.x & 7;
  const float* src;
  float* dst;
  if (row < B_ROWS) {
    src = x + (size_t)row * D_DIM;
    dst = x2 + row;
  } else {
    int r = row - B_ROWS;
    src = emb + (size_t)r * D_DIM;
    dst = e2 + r;
  }
  float v = src[lane];
  float t = v * v;
  asm volatile("" : "+v"(t));  // block fma contraction: term must be fl(v*v)
  float acc = t;
#pragma unroll
  for (int i = 1; i < 16; ++i) {
    float w = src[i * 8 + lane];
    float tt = w * w;
    asm volatile("" : "+v"(tt));
    acc = acc + tt;
  }
  // combine tree across the 8 lanes of this row
  acc = acc + __shfl_xor(acc, 1, 64);
  acc = acc + __shfl_xor(acc, 2, 64);
  acc = acc + __shfl_xor(acc, 4, 64);
  if (lane == 0) *dst = acc;
}

// ---------------------------------------------------------------------------
// Kernel 2: fused GEMM + argmin.
// Block: 256 threads, 128-row tile.  As[128(d)][128(m)] resident (64 KB).
// Bs[2][32(d)][128(n)] double-buffered (32 KB).  Micro-tile 8x8 per thread;
// b-fragment = codes {tx*4..tx*4+3} u {64+tx*4..+3} (keeps LDS reads <=2-way).
// dot accumulates d = 0..127 strictly in order with single-rounded FMA.
// score = fmaf(-2, dot, fl(x2+e2))  == fl((x2+e2) - 2*dot) bit-exactly.
// argmin: strict less-than, first index wins ties.
// ---------------------------------------------------------------------------
__global__ __launch_bounds__(256) void vq_argmin(const float* __restrict__ x,
                                                 const float* __restrict__ emb,
                                                 const float* __restrict__ x2,
                                                 const float* __restrict__ e2,
                                                 float* __restrict__ out_idx) {
  __shared__ float smem[128 * 128 + 2 * 32 * 128];  // 96 KB
  float* As = smem;                // [d][m]
  float* Bs = smem + 128 * 128;    // [buf][d][n]

  const int tid = threadIdx.x;
  const int tx = tid & 15;
  const int ty = tid >> 4;
  const int rowbase = blockIdx.x * 128;

  // ---- stage As: x[rowbase+m][d] -> As[d*128+m] (transpose; one-time) ----
  {
    int m = tid >> 1;
    int h = tid & 1;
    const float4* src = (const float4*)(x + (size_t)(rowbase + m) * 128 + h * 64);
#pragma unroll
    for (int p = 0; p < 16; ++p) {
      float4 v = src[p];
      int d = h * 64 + p * 4;
      As[(d + 0) * 128 + m] = v.x;
      As[(d + 1) * 128 + m] = v.y;
      As[(d + 2) * 128 + m] = v.z;
      As[(d + 3) * 128 + m] = v.w;
    }
  }

  float xs2[8];
#pragma unroll
  for (int i = 0; i < 8; ++i) xs2[i] = x2[rowbase + ty * 8 + i];

  float minv[8];
  int mini[8];
#pragma unroll
  for (int i = 0; i < 8; ++i) { minv[i] = 3.4e38f; mini[i] = 0; }

  const int n = tid >> 1;   // code row within chunk (0..127)
  const int h = tid & 1;    // which 16-d half of the 32-d slab
  float4 breg[4];

  // prefetch + store stage 0 (chunk 0, d-slab 0) into buf 0
  {
    const float4* src = (const float4*)(emb + (size_t)n * 128 + h * 16);
#pragma unroll
    for (int p = 0; p < 4; ++p) breg[p] = src[p];
#pragma unroll
    for (int p = 0; p < 4; ++p) {
      float* bp = Bs + (size_t)(h * 16 + p * 4) * 128 + n;
      bp[0] = breg[p].x; bp[128] = breg[p].y; bp[256] = breg[p].z; bp[384] = breg[p].w;
    }
  }

  float acc[8][8];
#pragma unroll
  for (int i = 0; i < 8; ++i)
#pragma unroll
    for (int j = 0; j < 8; ++j) acc[i][j] = 0.0f;

#pragma unroll 1
  for (int s = 0; s < 128; ++s) {   // s = chunk*4 + d-slab
    __syncthreads();
    if (s + 1 < 128) {  // prefetch next slab into regs (latency hidden by FMAs)
      int s1 = s + 1;
      const float4* src = (const float4*)(emb + (size_t)((s1 >> 2) * 128 + n) * 128 +
                                          (s1 & 3) * 32 + h * 16);
#pragma unroll
      for (int p = 0; p < 4; ++p) breg[p] = src[p];
    }
    const float* bbase = Bs + (size_t)(s & 1) * 4096;
    const float* abase = As + (size_t)(s & 3) * 32 * 128;
#pragma unroll 8
    for (int d = 0; d < 32; ++d) {
      float4 a0 = *(const float4*)(abase + d * 128 + ty * 8);
      float4 a1 = *(const float4*)(abase + d * 128 + ty * 8 + 4);
      float4 b0 = *(const float4*)(bbase + d * 128 + tx * 4);
      float4 b1 = *(const float4*)(bbase + d * 128 + tx * 4 + 64);
      float av[8] = {a0.x, a0.y, a0.z, a0.w, a1.x, a1.y, a1.z, a1.w};
      float bv[8] = {b0.x, b0.y, b0.z, b0.w, b1.x, b1.y, b1.z, b1.w};
#pragma unroll
      for (int i = 0; i < 8; ++i)
#pragma unroll
        for (int j = 0; j < 8; ++j)
          acc[i][j] = __builtin_fmaf(av[i], bv[j], acc[i][j]);
    }
    if (s + 1 < 128) {  // store prefetched slab into the other buffer
      float* bw = Bs + (size_t)((s + 1) & 1) * 4096;
#pragma unroll
      for (int p = 0; p < 4; ++p) {
        float* bp = bw + (size_t)(h * 16 + p * 4) * 128 + n;
        bp[0] = breg[p].x; bp[128] = breg[p].y; bp[256] = breg[p].z; bp[384] = breg[p].w;
      }
    }
    if ((s & 3) == 3) {  // chunk finished: score 128 codes, update argmin
      int kbase = (s >> 2) * 128;
      float e2r[8];
#pragma unroll
      for (int j = 0; j < 4; ++j) {
        e2r[j] = e2[kbase + tx * 4 + j];
        e2r[j + 4] = e2[kbase + 64 + tx * 4 + j];
      }
#pragma unroll
      for (int i = 0; i < 8; ++i) {
#pragma unroll
        for (int j = 0; j < 8; ++j) {
          float t1 = xs2[i] + e2r[j];                       // fl(x2+e2)
          float dsc = __builtin_fmaf(-2.0f, acc[i][j], t1); // fl(t1 - 2*dot)
          int idx = kbase + (j < 4 ? tx * 4 + j : 64 + tx * 4 + (j - 4));
          if (dsc < minv[i]) { minv[i] = dsc; mini[i] = idx; }  // first idx wins ties
          acc[i][j] = 0.0f;
        }
      }
    }
  }

  // ---- cross-thread reduction: 16 candidates per row ----
  __syncthreads();
  float* redv = smem;                  // reuse As region: [128][16]
  int* redi = (int*)(smem + 128 * 16); // [128][16]
#pragma unroll
  for (int i = 0; i < 8; ++i) {
    redv[(ty * 8 + i) * 16 + tx] = minv[i];
    redi[(ty * 8 + i) * 16 + tx] = mini[i];
  }
  __syncthreads();
  if (tid < 128) {
    int r = tid;
    float bv = redv[r * 16];
    int bi = redi[r * 16];
#pragma unroll
    for (int t = 1; t < 16; ++t) {
      float v = redv[r * 16 + t];
      int i2 = redi[r * 16 + t];
      if (v < bv || (v == bv && i2 < bi)) { bv = v; bi = i2; }
    }
    out_idx[rowbase + r] = (float)bi;
  }
}

// ---------------------------------------------------------------------------
// Kernel 3: gather + straight-through output + loss partials + histogram.
// st = fl(x + fl(q-x))  (NOT exactly q in fp32 — replicate elementwise).
// e-term = fl((q-x)^2), q-term = fl((st-x)^2); accumulate in double.
// ---------------------------------------------------------------------------
__global__ __launch_bounds__(256) void vq_gather(const float* __restrict__ x,
                                                 const float* __restrict__ emb,
                                                 const float* __restrict__ idxf,
                                                 float* __restrict__ out_q,
                                                 unsigned int* __restrict__ counts,
                                                 double* __restrict__ sums) {
  int r = blockIdx.x * 8 + (threadIdx.x >> 5);
  int lane = threadIdx.x & 31;
  int idx = (int)idxf[r];
  const float4 q = *(const float4*)(emb + (size_t)idx * 128 + lane * 4);
  const float4 xv = *(const float4*)(x + (size_t)r * 128 + lane * 4);
  float d0 = q.x - xv.x, d1 = q.y - xv.y, d2 = q.z - xv.z, d3 = q.w - xv.w;
  float s0 = xv.x + d0, s1 = xv.y + d1, s2 = xv.z + d2, s3 = xv.w + d3;
  float4 st = make_float4(s0, s1, s2, s3);
  *(float4*)(out_q + (size_t)r * 128 + lane * 4) = st;
  float g0 = s0 - xv.x, g1 = s1 - xv.y, g2 = s2 - xv.z, g3 = s3 - xv.w;
  double es = (double)(d0 * d0) + (double)(d1 * d1) + (double)(d2 * d2) + (double)(d3 * d3);
  double qs = (double)(g0 * g0) + (double)(g1 * g1) + (double)(g2 * g2) + (double)(g3 * g3);
#pragma unroll
  for (int off = 32; off >= 1; off >>= 1) {
    es += __shfl_down(es, off, 64);
    qs += __shfl_down(qs, off, 64);
  }
  __shared__ double lred[2][4];
  int w = threadIdx.x >> 6;
  if ((threadIdx.x & 63) == 0) { lred[0][w] = es; lred[1][w] = qs; }
  if (lane == 0) atomicAdd(&counts[idx], 1u);
  __syncthreads();
  if (threadIdx.x == 0) {
    double e = lred[0][0] + lred[0][1] + lred[0][2] + lred[0][3];
    double qq = lred[1][0] + lred[1][1] + lred[1][2] + lred[1][3];
    atomicAdd(&sums[0], e);
    atomicAdd(&sums[1], qq);
  }
}

// ---------------------------------------------------------------------------
// Kernel 4: finalize scalars (vq_loss, e_latent, q_latent, perplexity).
// p = count/32768 is exact (pow2 divide); term = fl(p * log(p + 1e-10)).
// ---------------------------------------------------------------------------
__global__ __launch_bounds__(256) void vq_final(const unsigned int* __restrict__ counts,
                                                const double* __restrict__ sums,
                                                float* __restrict__ out_scalars) {
  double s = 0.0;
  for (int k = threadIdx.x; k < K_CODES; k += 256) {
    float p = (float)counts[k] * (1.0f / 32768.0f);
    float term = p * logf(p + 1e-10f);
    s += (double)term;
  }
#pragma unroll
  for (int off = 32; off >= 1; off >>= 1) s += __shfl_down(s, off, 64);
  __shared__ double red[4];
  if ((threadIdx.x & 63) == 0) red[threadIdx.x >> 6] = s;
  __syncthreads();
  if (threadIdx.x == 0) {
    double tot = red[0] + red[1] + red[2] + red[3];
    float e_lat = (float)(sums[0] / (double)(B_ROWS * D_DIM));
    float q_lat = (float)(sums[1] / (double)(B_ROWS * D_DIM));
    float vq = q_lat + 0.25f * e_lat;   // fl(q + fl(0.25*e)); 0.25*e exact
    out_scalars[0] = vq;
    out_scalars[1] = e_lat;
    out_scalars[2] = q_lat;
    out_scalars[3] = expf(-(float)tot);
  }
}

extern "C" void kernel_launch(void* const* d_in, const int* in_sizes, int n_in,
                              void* d_out, int out_size, void* d_ws, size_t ws_size,
                              hipStream_t stream) {
  const float* x = (const float*)d_in[0];
  const float* emb = (const float*)d_in[1];
  float* out = (float*)d_out;

  // ws layout: counts[4096] u32 | sums[2] f64 | e2[4096] f32 | x2[32768] f32
  unsigned int* counts = (unsigned int*)d_ws;
  double* sums = (double*)((char*)d_ws + 16384);
  float* e2 = (float*)((char*)d_ws + 16400);
  float* x2 = (float*)((char*)d_ws + 16400 + 4 * K_CODES);

  float* out_idx = out + (size_t)B_ROWS * D_DIM;
  float* out_scalars = out_idx + B_ROWS;

  hipMemsetAsync(d_ws, 0, 16400, stream);  // zero counts + sums (ws is poisoned)
  sq_rows<<<(B_ROWS + K_CODES) / 32, 256, 0, stream>>>(x, emb, x2, e2);
  vq_argmin<<<B_ROWS / 128, 256, 0, stream>>>(x, emb, x2, e2, out_idx);
  vq_gather<<<B_ROWS / 8, 256, 0, stream>>>(x, emb, out_idx, out, counts, sums);
  vq_final<<<1, 256, 0, stream>>>(counts, sums, out_scalars);
}

// Round 2
// 575.968 us; speedup vs baseline: 1.1358x; 1.1358x over previous
//
#include <hip/hip_runtime.h>
#include <math.h>

#define B_ROWS 32768
#define K_CODES 4096
#define D_DIM 128

// ---------------------------------------------------------------------------
// Kernel 1: row sums of squares, replicating numpy pairwise_sum for n=128:
// 8 strided accumulators r[j] = sum_{i = j mod 8} fl(x_i*x_i), then
// ((r0+r1)+(r2+r3)) + ((r4+r5)+(r6+r7)).  8 lanes per row; xor-tree matches
// the combine exactly (fp add is commutative bitwise).
// ---------------------------------------------------------------------------
__global__ __launch_bounds__(256) void sq_rows(const float* __restrict__ x,
                                               const float* __restrict__ emb,
                                               float* __restrict__ x2,
                                               float* __restrict__ e2) {
  int row = blockIdx.x * 32 + (threadIdx.x >> 3);
  int lane = threadIdx.x & 7;
  const float* src;
  float* dst;
  if (row < B_ROWS) {
    src = x + (size_t)row * D_DIM;
    dst = x2 + row;
  } else {
    int r = row - B_ROWS;
    src = emb + (size_t)r * D_DIM;
    dst = e2 + r;
  }
  float v = src[lane];
  float t = v * v;
  asm volatile("" : "+v"(t));  // block fma contraction: term must be fl(v*v)
  float acc = t;
#pragma unroll
  for (int i = 1; i < 16; ++i) {
    float w = src[i * 8 + lane];
    float tt = w * w;
    asm volatile("" : "+v"(tt));
    acc = acc + tt;
  }
  // combine tree across the 8 lanes of this row
  acc = acc + __shfl_xor(acc, 1, 64);
  acc = acc + __shfl_xor(acc, 2, 64);
  acc = acc + __shfl_xor(acc, 4, 64);
  if (lane == 0) *dst = acc;
}

// ---------------------------------------------------------------------------
// Kernel 2: fused GEMM + argmin.
// Block: 512 threads (8 waves -> 2 waves/SIMD at 1 block/CU), 128-row tile.
// As[128(d)][128(m)] resident (64 KB).  Bs[2][32(d)][256(n)] double-buffered
// (64 KB).  Total LDS 128 KB.  Micro-tile 8x8 per thread over a 128x256
// chunk; b-fragment = codes {tx*4..+3} u {128+tx*4..+3}.
// dot accumulates d = 0..127 strictly in order with single-rounded FMA.
// score = fmaf(-2, dot, fl(x2+e2))  == fl((x2+e2) - 2*dot) bit-exactly.
// argmin: strict less-than, first index wins ties (thread-local candidate
// indices ascend in iteration order, cross-thread reduce tie-breaks on idx).
// ---------------------------------------------------------------------------
__global__ __launch_bounds__(512) void vq_argmin(const float* __restrict__ x,
                                                 const float* __restrict__ emb,
                                                 const float* __restrict__ x2,
                                                 const float* __restrict__ e2,
                                                 float* __restrict__ out_idx) {
  __shared__ float smem[128 * 128 + 2 * 32 * 256];  // 128 KB
  float* As = smem;                // [d][m]
  float* Bs = smem + 128 * 128;    // [buf][d][n]

  const int tid = threadIdx.x;
  const int tx = tid & 31;   // n-direction: 32 groups
  const int ty = tid >> 5;   // m-direction: 16 groups of 8 rows
  const int rowbase = blockIdx.x * 128;

  // ---- stage As: x[rowbase+m][d] -> As[d*128+m] (transpose; one-time) ----
  {
    int m = tid >> 2;        // 0..127
    int q = tid & 3;         // 32-d quarter
    const float4* src = (const float4*)(x + (size_t)(rowbase + m) * 128 + q * 32);
#pragma unroll
    for (int p = 0; p < 8; ++p) {
      float4 v = src[p];
      int d = q * 32 + p * 4;
      As[(d + 0) * 128 + m] = v.x;
      As[(d + 1) * 128 + m] = v.y;
      As[(d + 2) * 128 + m] = v.z;
      As[(d + 3) * 128 + m] = v.w;
    }
  }

  float xs2[8];
#pragma unroll
  for (int i = 0; i < 8; ++i) xs2[i] = x2[rowbase + ty * 8 + i];

  float minv[8];
  int mini[8];
#pragma unroll
  for (int i = 0; i < 8; ++i) { minv[i] = 3.4e38f; mini[i] = 0; }

  const int n = tid >> 1;   // code row within 256-chunk (0..255)
  const int h = tid & 1;    // which 16-d half of the 32-d slab
  float4 breg[4];

  // prefetch + store stage 0 (chunk 0, d-slab 0) into buf 0
  {
    const float4* src = (const float4*)(emb + (size_t)n * 128 + h * 16);
#pragma unroll
    for (int p = 0; p < 4; ++p) breg[p] = src[p];
#pragma unroll
    for (int p = 0; p < 4; ++p) {
      float* bp = Bs + (size_t)(h * 16 + p * 4) * 256 + n;
      bp[0] = breg[p].x; bp[256] = breg[p].y; bp[512] = breg[p].z; bp[768] = breg[p].w;
    }
  }

  float acc[8][8];
#pragma unroll
  for (int i = 0; i < 8; ++i)
#pragma unroll
    for (int j = 0; j < 8; ++j) acc[i][j] = 0.0f;

#pragma unroll 1
  for (int s = 0; s < 64; ++s) {   // s = chunk*4 + d-slab; chunk = 256 codes
    __syncthreads();
    if (s + 1 < 64) {  // prefetch next slab into regs (latency hidden by FMAs)
      int s1 = s + 1;
      const float4* src = (const float4*)(emb + (size_t)((s1 >> 2) * 256 + n) * 128 +
                                          (s1 & 3) * 32 + h * 16);
#pragma unroll
      for (int p = 0; p < 4; ++p) breg[p] = src[p];
    }
    const float* bbase = Bs + (size_t)(s & 1) * 8192;
    const float* abase = As + (size_t)(s & 3) * 32 * 128;
#pragma unroll 8
    for (int d = 0; d < 32; ++d) {
      float4 a0 = *(const float4*)(abase + d * 128 + ty * 8);
      float4 a1 = *(const float4*)(abase + d * 128 + ty * 8 + 4);
      float4 b0 = *(const float4*)(bbase + d * 256 + tx * 4);
      float4 b1 = *(const float4*)(bbase + d * 256 + tx * 4 + 128);
      float av[8] = {a0.x, a0.y, a0.z, a0.w, a1.x, a1.y, a1.z, a1.w};
      float bv[8] = {b0.x, b0.y, b0.z, b0.w, b1.x, b1.y, b1.z, b1.w};
#pragma unroll
      for (int i = 0; i < 8; ++i)
#pragma unroll
        for (int j = 0; j < 8; ++j)
          acc[i][j] = __builtin_fmaf(av[i], bv[j], acc[i][j]);
    }
    if (s + 1 < 64) {  // store prefetched slab into the other buffer
      float* bw = Bs + (size_t)((s + 1) & 1) * 8192;
#pragma unroll
      for (int p = 0; p < 4; ++p) {
        float* bp = bw + (size_t)(h * 16 + p * 4) * 256 + n;
        bp[0] = breg[p].x; bp[256] = breg[p].y; bp[512] = breg[p].z; bp[768] = breg[p].w;
      }
    }
    if ((s & 3) == 3) {  // chunk finished: score 256 codes, update argmin
      int kbase = (s >> 2) * 256;
      float e2r[8];
#pragma unroll
      for (int j = 0; j < 4; ++j) {
        e2r[j] = e2[kbase + tx * 4 + j];
        e2r[j + 4] = e2[kbase + 128 + tx * 4 + j];
      }
#pragma unroll
      for (int i = 0; i < 8; ++i) {
#pragma unroll
        for (int j = 0; j < 8; ++j) {
          float t1 = xs2[i] + e2r[j];                       // fl(x2+e2)
          float dsc = __builtin_fmaf(-2.0f, acc[i][j], t1); // fl(t1 - 2*dot)
          int idx = kbase + (j < 4 ? tx * 4 + j : 128 + tx * 4 + (j - 4));
          if (dsc < minv[i]) { minv[i] = dsc; mini[i] = idx; }  // first idx wins ties
          acc[i][j] = 0.0f;
        }
      }
    }
  }

  // ---- cross-thread reduction: 32 candidates per row ----
  __syncthreads();
  float* redv = smem;                       // reuse As region: [128][32]
  int* redi = (int*)(smem + 128 * 32);      // [128][32]
#pragma unroll
  for (int i = 0; i < 8; ++i) {
    redv[(ty * 8 + i) * 32 + tx] = minv[i];
    redi[(ty * 8 + i) * 32 + tx] = mini[i];
  }
  __syncthreads();
  if (tid < 128) {
    int r = tid;
    float bv = redv[r * 32];
    int bi = redi[r * 32];
#pragma unroll
    for (int t = 1; t < 32; ++t) {
      float v = redv[r * 32 + t];
      int i2 = redi[r * 32 + t];
      if (v < bv || (v == bv && i2 < bi)) { bv = v; bi = i2; }
    }
    out_idx[rowbase + r] = (float)bi;
  }
}

// ---------------------------------------------------------------------------
// Kernel 3: gather + straight-through output + loss partials + histogram.
// st = fl(x + fl(q-x))  (NOT exactly q in fp32 — replicate elementwise).
// e-term = fl((q-x)^2), q-term = fl((st-x)^2); accumulate in double.
// Cross-row mixing in the wave shuffle is fine: only the total sum matters.
// ---------------------------------------------------------------------------
__global__ __launch_bounds__(256) void vq_gather(const float* __restrict__ x,
                                                 const float* __restrict__ emb,
                                                 const float* __restrict__ idxf,
                                                 float* __restrict__ out_q,
                                                 unsigned int* __restrict__ counts,
                                                 double* __restrict__ sums) {
  int r = blockIdx.x * 8 + (threadIdx.x >> 5);
  int lane = threadIdx.x & 31;
  int idx = (int)idxf[r];
  const float4 q = *(const float4*)(emb + (size_t)idx * 128 + lane * 4);
  const float4 xv = *(const float4*)(x + (size_t)r * 128 + lane * 4);
  float d0 = q.x - xv.x, d1 = q.y - xv.y, d2 = q.z - xv.z, d3 = q.w - xv.w;
  float s0 = xv.x + d0, s1 = xv.y + d1, s2 = xv.z + d2, s3 = xv.w + d3;
  float4 st = make_float4(s0, s1, s2, s3);
  *(float4*)(out_q + (size_t)r * 128 + lane * 4) = st;
  float g0 = s0 - xv.x, g1 = s1 - xv.y, g2 = s2 - xv.z, g3 = s3 - xv.w;
  double es = (double)(d0 * d0) + (double)(d1 * d1) + (double)(d2 * d2) + (double)(d3 * d3);
  double qs = (double)(g0 * g0) + (double)(g1 * g1) + (double)(g2 * g2) + (double)(g3 * g3);
#pragma unroll
  for (int off = 32; off >= 1; off >>= 1) {
    es += __shfl_down(es, off, 64);
    qs += __shfl_down(qs, off, 64);
  }
  __shared__ double lred[2][4];
  int w = threadIdx.x >> 6;
  if ((threadIdx.x & 63) == 0) { lred[0][w] = es; lred[1][w] = qs; }
  if (lane == 0) atomicAdd(&counts[idx], 1u);
  __syncthreads();
  if (threadIdx.x == 0) {
    double e = lred[0][0] + lred[0][1] + lred[0][2] + lred[0][3];
    double qq = lred[1][0] + lred[1][1] + lred[1][2] + lred[1][3];
    atomicAdd(&sums[0], e);
    atomicAdd(&sums[1], qq);
  }
}

// ---------------------------------------------------------------------------
// Kernel 4: finalize scalars (vq_loss, e_latent, q_latent, perplexity).
// p = count/32768 is exact (pow2 divide); term = fl(p * log(p + 1e-10)).
// ---------------------------------------------------------------------------
__global__ __launch_bounds__(256) void vq_final(const unsigned int* __restrict__ counts,
                                                const double* __restrict__ sums,
                                                float* __restrict__ out_scalars) {
  double s = 0.0;
  for (int k = threadIdx.x; k < K_CODES; k += 256) {
    float p = (float)counts[k] * (1.0f / 32768.0f);
    float term = p * logf(p + 1e-10f);
    s += (double)term;
  }
#pragma unroll
  for (int off = 32; off >= 1; off >>= 1) s += __shfl_down(s, off, 64);
  __shared__ double red[4];
  if ((threadIdx.x & 63) == 0) red[threadIdx.x >> 6] = s;
  __syncthreads();
  if (threadIdx.x == 0) {
    double tot = red[0] + red[1] + red[2] + red[3];
    float e_lat = (float)(sums[0] / (double)(B_ROWS * D_DIM));
    float q_lat = (float)(sums[1] / (double)(B_ROWS * D_DIM));
    float vq = q_lat + 0.25f * e_lat;   // fl(q + fl(0.25*e)); 0.25*e exact
    out_scalars[0] = vq;
    out_scalars[1] = e_lat;
    out_scalars[2] = q_lat;
    out_scalars[3] = expf(-(float)tot);
  }
}

extern "C" void kernel_launch(void* const* d_in, const int* in_sizes, int n_in,
                              void* d_out, int out_size, void* d_ws, size_t ws_size,
                              hipStream_t stream) {
  const float* x = (const float*)d_in[0];
  const float* emb = (const float*)d_in[1];
  float* out = (float*)d_out;

  // ws layout: counts[4096] u32 | sums[2] f64 | e2[4096] f32 | x2[32768] f32
  unsigned int* counts = (unsigned int*)d_ws;
  double* sums = (double*)((char*)d_ws + 16384);
  float* e2 = (float*)((char*)d_ws + 16400);
  float* x2 = (float*)((char*)d_ws + 16400 + 4 * K_CODES);

  float* out_idx = out + (size_t)B_ROWS * D_DIM;
  float* out_scalars = out_idx + B_ROWS;

  hipMemsetAsync(d_ws, 0, 16400, stream);  // zero counts + sums (ws is poisoned)
  sq_rows<<<(B_ROWS + K_CODES) / 32, 256, 0, stream>>>(x, emb, x2, e2);
  vq_argmin<<<B_ROWS / 128, 512, 0, stream>>>(x, emb, x2, e2, out_idx);
  vq_gather<<<B_ROWS / 8, 256, 0, stream>>>(x, emb, out_idx, out, counts, sums);
  vq_final<<<1, 256, 0, stream>>>(counts, sums, out_scalars);
}